// Round 14
// baseline (1000.065 us; speedup 1.0000x reference)
//
#include <hip/hip_runtime.h>

typedef __fp16 f16;
typedef __fp16 f16x4 __attribute__((ext_vector_type(4)));
typedef __fp16 f16x8 __attribute__((ext_vector_type(8)));
typedef float  f32x4 __attribute__((ext_vector_type(4)));
typedef unsigned long long ull;

#define DEV static __device__ __forceinline__

DEV f32x4 mfma16(f16x4 a, f16x4 b, f32x4 c) {
  return __builtin_amdgcn_mfma_f32_16x16x16f16(a, b, c, 0, 0, 0);
}
DEV f16x4 lo4(f16x8 v) { return __builtin_shufflevector(v, v, 0, 1, 2, 3); }
DEV f16x4 hi4(f16x8 v) { return __builtin_shufflevector(v, v, 4, 5, 6, 7); }
DEV float sigf(float x) { return 1.f / (1.f + __expf(-x)); }
DEV float tanh_(float x) { float e = __expf(2.f * x); return 1.f - 2.f / (e + 1.f); }

union U8 { float4 f4; float2 f2[2]; };
union H2 { unsigned u; f16 h[2]; };
union H4 { ull u; f16 h[4]; f16x4 v; };
union U32F { unsigned u; float f; };

#define HB 32768   // f16 elements in a [64][512] buffer

// ---- agent-coherent (L2-bypassing) helpers ----
DEV ull ldU(const ull* p) {
  return __hip_atomic_load(p, __ATOMIC_RELAXED, __HIP_MEMORY_SCOPE_AGENT);
}
DEV unsigned ldF(const unsigned* p) {
  return __hip_atomic_load(p, __ATOMIC_RELAXED, __HIP_MEMORY_SCOPE_AGENT);
}
DEV void stU32(unsigned* p, unsigned v) {
  __hip_atomic_store(p, v, __ATOMIC_RELAXED, __HIP_MEMORY_SCOPE_AGENT);
}
DEV void stU64(ull* p, ull v) {
  __hip_atomic_store(p, v, __ATOMIC_RELAXED, __HIP_MEMORY_SCOPE_AGENT);
}

// 8-slot line poll (lanes 0-7), then block barrier
DEV void wait8(const unsigned* line, unsigned tgt) {
  if (threadIdx.x < 8)
    while (ldF(line + threadIdx.x * 16) < tgt) {}
  __syncthreads();
}

DEV void signalDone(unsigned* line, int slot) {
  asm volatile("s_waitcnt vmcnt(0)" ::: "memory");  // drain stores (per wave)
  __syncthreads();
  if (threadIdx.x == 0)
    __hip_atomic_fetch_add(line + slot * 16, 1u, __ATOMIC_RELAXED, __HIP_MEMORY_SCOPE_AGENT);
}

// single-counter signal (tail)
DEV void signalOne(unsigned* ctr) {
  asm volatile("s_waitcnt vmcnt(0)" ::: "memory");
  __syncthreads();
  if (threadIdx.x == 0)
    __hip_atomic_fetch_add(ctr, 1u, __ATOMIC_RELAXED, __HIP_MEMORY_SCOPE_AGENT);
}

// k-permuted staging of 16 f16 (cached path)
DEV void stageRow(const f16* __restrict__ s, f16* __restrict__ dstRow, int ch) {
  U8 u0, u1;
  u0.f4 = *(const float4*)s;
  u1.f4 = *(const float4*)(s + 8);
  *(float2*)(dstRow +  0 + ch * 4) = u0.f2[0];
  *(float2*)(dstRow + 16 + ch * 4) = u0.f2[1];
  *(float2*)(dstRow + 32 + ch * 4) = u1.f2[0];
  *(float2*)(dstRow + 48 + ch * 4) = u1.f2[1];
}

// cached stage with per-row source pointer (row = tid>>2)
DEV void stageAp(const f16* __restrict__ rowSrc, f16 (*A)[64][72], int tid) {
  int ch = tid & 3;
  const f16* s = rowSrc + ch * 16;
#pragma unroll
  for (int c = 0; c < 8; ++c)
    stageRow(s + c * 64, &A[c][tid >> 2][0], ch);
}

// coherent stage of [64][512] A into sA[8][64][72]
DEV void stageAu(const ull* __restrict__ srcU, f16 (*A)[64][72], int tid) {
  int row = tid >> 2, ch = tid & 3;
  const ull* s = srcU + row * 128 + ch * 4;
#pragma unroll
  for (int c = 0; c < 8; ++c) {
    ull d0 = ldU(s + c * 16 + 0);
    ull d1 = ldU(s + c * 16 + 1);
    ull d2 = ldU(s + c * 16 + 2);
    ull d3 = ldU(s + c * 16 + 3);
    f16* d = &A[c][row][0];
    *(ull*)(d +  0 + ch * 4) = d0;
    *(ull*)(d + 16 + ch * 4) = d1;
    *(ull*)(d + 32 + ch * 4) = d2;
    *(ull*)(d + 48 + ch * 4) = d3;
  }
}

// 64x32 output tile: wave (mh,ns); acc[2]
DEV void kloop32(const f16 (*Wt)[32][72], const f16 (*A)[64][72],
                 int mh, int ns, int m16, int g4, f32x4 acc[2]) {
#pragma unroll
  for (int c = 0; c < 8; ++c) {
#pragma unroll
    for (int half = 0; half < 2; ++half) {
      f16x8 bf = *(const f16x8*)&Wt[c][ns * 16 + m16][g4 * 16 + half * 8];
      f16x4 bl = lo4(bf), bh = hi4(bf);
#pragma unroll
      for (int mt = 0; mt < 2; ++mt) {
        f16x8 af = *(const f16x8*)&A[c][mh * 32 + mt * 16 + m16][g4 * 16 + half * 8];
        acc[mt] = mfma16(lo4(af), bl, acc[mt]);
        acc[mt] = mfma16(hi4(af), bh, acc[mt]);
      }
    }
  }
}

// 64x64 output tile: wave = n-16-group; acc[4]
DEV void kloop64(const f16* Wg, const f16 (*A)[64][72],
                 int nsG, int m16, int g4, f32x4 acc[4]) {
#pragma unroll
  for (int c = 0; c < 8; ++c) {
#pragma unroll
    for (int half = 0; half < 2; ++half) {
      f16x8 bf = *(const f16x8*)&Wg[((size_t)(c * 64 + nsG * 16 + m16)) * 72 + g4 * 16 + half * 8];
      f16x4 bl = lo4(bf), bh = hi4(bf);
#pragma unroll
      for (int mt = 0; mt < 4; ++mt) {
        f16x8 af = *(const f16x8*)&A[c][mt * 16 + m16][g4 * 16 + half * 8];
        acc[mt] = mfma16(lo4(af), bl, acc[mt]);
        acc[mt] = mfma16(hi4(af), bh, acc[mt]);
      }
    }
  }
}

// ---------------- conv tile core (MFMA accumulate) ----------------
DEV void convCore(char* smem, int tile, const f16* __restrict__ cfT,
                  const f16* __restrict__ wc9, f32x4 acc[15][2]) {
  f16 (*At)[40] = (f16(*)[40])smem;                 // [240][40]
  f16 (*Bt)[40] = (f16(*)[40])(smem + 19200);       // [128][40]
  const int t = threadIdx.x, lane = t & 63, w = t >> 6;
  const int b = tile >> 2, eb = (tile & 3) * 128;
  const int m16 = lane & 15, g4 = lane >> 4;

  for (int kr = 0; kr < 9; ++kr) {
    int dh = kr / 3 - 1, dw = kr % 3 - 1;
    for (int f0 = 0; f0 < 512; f0 += 32) {
      __syncthreads();
      if (t < 240) {
        int hh = t / 40 + dh, ww = t % 40 + dw;
        if (hh >= 0 && hh < 6 && ww >= 0 && ww < 40) {
          const f16* s = cfT + ((size_t)(b * 240 + hh * 40 + ww) * 512 + f0);
          U8 u0, u1, u2, u3;
          u0.f4 = *(const float4*)s;        u1.f4 = *(const float4*)(s + 8);
          u2.f4 = *(const float4*)(s + 16); u3.f4 = *(const float4*)(s + 24);
          *(float2*)&At[t][ 0] = u0.f2[0];
          *(float2*)&At[t][ 8] = u0.f2[1];
          *(float2*)&At[t][16] = u1.f2[0];
          *(float2*)&At[t][24] = u1.f2[1];
          *(float2*)&At[t][ 4] = u2.f2[0];
          *(float2*)&At[t][12] = u2.f2[1];
          *(float2*)&At[t][20] = u3.f2[0];
          *(float2*)&At[t][28] = u3.f2[1];
        } else {
          float2 z = make_float2(0.f, 0.f);
          *(float2*)&At[t][ 0] = z; *(float2*)&At[t][ 8] = z;
          *(float2*)&At[t][16] = z; *(float2*)&At[t][24] = z;
          *(float2*)&At[t][ 4] = z; *(float2*)&At[t][12] = z;
          *(float2*)&At[t][20] = z; *(float2*)&At[t][28] = z;
        }
      }
      {
        int n = t >> 1, ch = t & 1;
        const f16* s = wc9 + (size_t)(eb + n) * 4608 + kr * 512 + f0 + ch * 16;
        U8 u0, u1;
        u0.f4 = *(const float4*)s; u1.f4 = *(const float4*)(s + 8);
        *(float2*)&Bt[n][ 0 + ch * 4] = u0.f2[0];
        *(float2*)&Bt[n][ 8 + ch * 4] = u0.f2[1];
        *(float2*)&Bt[n][16 + ch * 4] = u1.f2[0];
        *(float2*)&Bt[n][24 + ch * 4] = u1.f2[1];
      }
      __syncthreads();
      f16x8 b0 = *(const f16x8*)&Bt[w * 32 + m16][g4 * 8];
      f16x8 b1v = *(const f16x8*)&Bt[w * 32 + 16 + m16][g4 * 8];
      f16x4 b0l = lo4(b0), b0h = hi4(b0), b1l = lo4(b1v), b1h = hi4(b1v);
#pragma unroll
      for (int mt = 0; mt < 15; ++mt) {
        f16x8 af = *(const f16x8*)&At[mt * 16 + m16][g4 * 8];
        f16x4 al = lo4(af), ah = hi4(af);
        acc[mt][0] = mfma16(al, b0l, acc[mt][0]);
        acc[mt][1] = mfma16(al, b1l, acc[mt][1]);
        acc[mt][0] = mfma16(ah, b0h, acc[mt][0]);
        acc[mt][1] = mfma16(ah, b1h, acc[mt][1]);
      }
    }
  }
}

// cached epilogue (enc: consumers in later kernels)
DEV void convTileC(char* smem, int tile, const f16* __restrict__ cfT,
                   const f16* __restrict__ wc9, const float* __restrict__ cb,
                   f16* __restrict__ xemH) {
  f32x4 acc[15][2] = {};
  convCore(smem, tile, cfT, wc9, acc);
  const int t = threadIdx.x, lane = t & 63, w = t >> 6;
  const int b = tile >> 2, eb = (tile & 3) * 128;
  const int m16 = lane & 15, g4 = lane >> 4;
#pragma unroll
  for (int nt = 0; nt < 2; ++nt) {
    int e = eb + w * 32 + nt * 16 + m16;
    float bias = cb[e];
#pragma unroll
    for (int mt = 0; mt < 15; ++mt)
#pragma unroll
      for (int r = 0; r < 4; ++r) {
        int p = mt * 16 + g4 * 4 + r;
        xemH[((size_t)(b * 240 + p)) * 512 + e] = (f16)(acc[mt][nt][r] + bias);
      }
  }
}

// agent epilogue (dec: consumers in same kernel)
DEV void convTileA(char* smem, int tile, const f16* __restrict__ cfT,
                   const f16* __restrict__ wc9, const float* __restrict__ cb,
                   f16* __restrict__ xemH) {
  f32x4 acc[15][2] = {};
  convCore(smem, tile, cfT, wc9, acc);
  const int t = threadIdx.x, lane = t & 63, w = t >> 6;
  const int b = tile >> 2, eb = (tile & 3) * 128;
  const int m16 = lane & 15, g4 = lane >> 4;
  f16 (*sC)[132] = (f16(*)[132])smem;   // [240][132]
  __syncthreads();
#pragma unroll
  for (int nt = 0; nt < 2; ++nt) {
    int e = eb + w * 32 + nt * 16 + m16;
    float bias = cb[e];
#pragma unroll
    for (int mt = 0; mt < 15; ++mt)
#pragma unroll
      for (int r = 0; r < 4; ++r)
        sC[mt * 16 + g4 * 4 + r][w * 32 + nt * 16 + m16] = (f16)(acc[mt][nt][r] + bias);
  }
  __syncthreads();
#pragma unroll
  for (int k = 0; k < 30; ++k) {
    int id = t + k * 256;             // 7680 chunks of 4 f16
    int row = id >> 5, chk = id & 31;
    H4 pk; pk.v = *(const f16x4*)&sC[row][chk * 4];
    stU64((ull*)xemH + (size_t)(b * 240 + row) * 128 + (eb >> 2) + chk, pk.u);
  }
}

// ---------------- merged prologue: wc9 + convW + convS + zero ----------------
__global__ __launch_bounds__(256) void k_prep(
    const float* __restrict__ att_cw, f16* __restrict__ wc9,
    const float* __restrict__ s0, const float* __restrict__ s1,
    const float* __restrict__ s2, const float* __restrict__ s3,
    f16* __restrict__ d0, f16* __restrict__ d1,
    f16* __restrict__ d2, f16* __restrict__ d3,
    const float* __restrict__ awhS, const float* __restrict__ embS,
    const float* __restrict__ outwS,
    f16* __restrict__ awhD, f16* __restrict__ embD, f16* __restrict__ outwD,
    unsigned* __restrict__ z0, unsigned* __restrict__ z1, unsigned* __restrict__ z2,
    unsigned* __restrict__ z3, unsigned* __restrict__ z4, unsigned* __restrict__ z5)
{
  const int bid = blockIdx.x, tid = threadIdx.x;
  if (bid < 512) {
    __shared__ float s[4608];
    const int e = bid;
    for (int i = tid; i < 4608; i += 256) s[i] = att_cw[(size_t)e * 4608 + i];
    __syncthreads();
    for (int j = tid; j < 4608; j += 256) {
      int rr = j >> 9, f = j & 511;
      wc9[(size_t)e * 4608 + j] = (f16)s[f * 9 + rr];
    }
  } else if (bid < 8704) {
    int i = (bid - 512) * 256 + tid;
    int sel = i >> 19, j = i & 524287;
    const float* s = sel == 0 ? s0 : sel == 1 ? s1 : sel == 2 ? s2 : s3;
    f16* d = sel == 0 ? d0 : sel == 1 ? d1 : sel == 2 ? d2 : d3;
    float4 v = ((const float4*)s)[j];
    f16x4 o = { (f16)v.x, (f16)v.y, (f16)v.z, (f16)v.w };
    *(f16x4*)(d + (size_t)j * 4) = o;
  } else if (bid < 9104) {
    int i = (bid - 8704) * 256 + tid;
    const float* s; f16* d; int j;
    if (i < 65536) { s = awhS; d = awhD; j = i; }
    else if (i < 65536 + 12288) { s = embS; d = embD; j = i - 65536; }
    else if (i < 65536 + 12288 + 24576) { s = outwS; d = outwD; j = i - 65536 - 12288; }
    else return;
    float4 v = ((const float4*)s)[j];
    f16x4 o = { (f16)v.x, (f16)v.y, (f16)v.z, (f16)v.w };
    *(f16x4*)(d + (size_t)j * 4) = o;
  } else {
    int i = (bid - 9104) * 256 + tid;
    int sel = i >> 14, j = i & 16383;
    unsigned* p = sel == 0 ? z0 : sel == 1 ? z1 : sel == 2 ? z2 :
                  sel == 3 ? z3 : sel == 4 ? z4 : z5;
    p[j] = 0;
  }
}

__global__ __launch_bounds__(256) void k_cfmx(
    const float* __restrict__ cf, f16* __restrict__ cfT, f16* __restrict__ xseq)
{
  __shared__ float sT[64][244];
  const int tid = threadIdx.x;
  const int f0 = blockIdx.x * 64, b = blockIdx.y;
  const float* src = cf + ((size_t)b * 512 + f0) * 240;
  for (int i = tid; i < 3840; i += 256) {
    float4 v = ((const float4*)src)[i];
    int fl = i / 60, pc = (i % 60) * 4;
    sT[fl][pc] = v.x; sT[fl][pc + 1] = v.y; sT[fl][pc + 2] = v.z; sT[fl][pc + 3] = v.w;
  }
  __syncthreads();
  if (tid < 240) {
    int p = tid;
    f16* drow = cfT + ((size_t)b * 240 + p) * 512 + f0;
#pragma unroll
    for (int j = 0; j < 8; ++j) {
      f16x8 o;
#pragma unroll
      for (int k = 0; k < 8; ++k) o[k] = (f16)sT[j * 8 + k][p];
      *(f16x8*)(drow + j * 8) = o;
    }
  }
  {
    int fl = tid >> 2, wq = tid & 3;
#pragma unroll
    for (int wi = 0; wi < 10; ++wi) {
      int w = wq * 10 + wi;
      float m = sT[fl][w];
#pragma unroll
      for (int h = 1; h < 6; ++h) m = fmaxf(m, sT[fl][h * 40 + w]);
      xseq[((size_t)w * 64 + b) * 512 + f0 + fl] = (f16)m;
    }
  }
}

// ---------------- batched X0 GEMM (encoder) ----------------
__global__ __launch_bounds__(256) void k_gemmX(
    const f16* __restrict__ A, const f16* __restrict__ W,
    const float* __restrict__ b1, const float* __restrict__ b2,
    f16* __restrict__ C)
{
  __shared__ f16 At[64][72];
  __shared__ f16 Bt[64][72];
  const int t = threadIdx.x, lane = t & 63, g = t >> 6;
  f32x4 acc[4] = {};
  const int m16 = lane & 15, g4 = lane >> 4;
  const size_t arow0 = (size_t)blockIdx.x * 64;

  for (int k0 = 0; k0 < 512; k0 += 64) {
    __syncthreads();
    { int row = t >> 2, ch = t & 3;
      stageRow(A + (arow0 + row) * 512 + k0 + ch * 16, &At[row][0], ch); }
    { int row = t >> 2, ch = t & 3;
      stageRow(W + ((size_t)blockIdx.y * 64 + row) * 512 + k0 + ch * 16, &Bt[row][0], ch); }
    __syncthreads();
#pragma unroll
    for (int half = 0; half < 2; ++half) {
      f16x8 bf = *(const f16x8*)&Bt[g * 16 + m16][g4 * 16 + half * 8];
      f16x4 bl = lo4(bf), bh = hi4(bf);
#pragma unroll
      for (int mt = 0; mt < 4; ++mt) {
        f16x8 af = *(const f16x8*)&At[mt * 16 + m16][g4 * 16 + half * 8];
        acc[mt] = mfma16(lo4(af), bl, acc[mt]);
        acc[mt] = mfma16(hi4(af), bh, acc[mt]);
      }
    }
  }
  int e = blockIdx.y * 64 + g * 16 + m16;
  float bias = b1[e] + b2[e];
#pragma unroll
  for (int mt = 0; mt < 4; ++mt)
#pragma unroll
    for (int r = 0; r < 4; ++r)
      C[(arow0 + mt * 16 + g4 * 4 + r) * 2048 + e] = (f16)(acc[mt][r] + bias);
}

// ---------------- persistent 2-layer LSTM + roles (+ dec tail) ----------------
// mode 0 (enc, 256 blocks): [0,32)L0 [32,96)L1 [96,224)conv(0..127) [224,256)X0de(tt>=1)
// mode 1 (dec, 232 blocks): [0,32)L0 [32,96)L1 [96,224)conv(128..255)A [224,232)X0t0+gemmG
//   then ALL dec blocks run the post-pass tail (score -> smctx -> logit -> loss)
// cntD dword map: lineL0[t]=t*128  lineL1[t]=(32+t)*128  lineX0=8192
//   cvb[b]=8320+b*16  gGd=9344  scb[b]=9360+b*16  smd[tq]=10384+tq*16  lgd=10448
__global__ __launch_bounds__(256, 1) void k_lstm(
    int T, int mode,
    const f16* __restrict__ G0, const f16* __restrict__ whh0,
    const f16* __restrict__ wih1, const f16* __restrict__ whh1,
    const float* __restrict__ bih1, const float* __restrict__ bhh1,
    f16* __restrict__ h0seq, f16* __restrict__ h1seq,
    unsigned* __restrict__ cnt,
    const f16* __restrict__ cfT, const f16* __restrict__ wc9,
    const float* __restrict__ cb, f16* __restrict__ xemH, int convBase,
    f16* __restrict__ X0de, const f16* __restrict__ wihD0,
    const float* __restrict__ bihD0, const float* __restrict__ bhhD0,
    const f16* __restrict__ emb, const int* __restrict__ tgt,
    const f16* __restrict__ x_t0,
    const f16* __restrict__ awh, const float* __restrict__ gbias, f16* __restrict__ gAll,
    const float* __restrict__ wv, const f16* __restrict__ outwH,
    const float* __restrict__ outb,
    float* __restrict__ escAll, f16* __restrict__ ctxAll,
    float* __restrict__ nllb, float* __restrict__ out)
{
  __shared__ __align__(16) char smem[147456];
  const int tid = threadIdx.x, lane = tid & 63, w = tid >> 6;
  const int m16 = lane & 15, g4 = lane >> 4;
  const int bid = blockIdx.x;

  if (bid < 32) {  // ---------- layer 0 ----------
    f16 (*sW)[64][72] = (f16(*)[64][72])smem;
    f16 (*sA)[64][72] = (f16(*)[64][72])(smem + 73728);
    float* sG = (float*)(smem + 73728);   // [4][64][17]
    const int utile = bid;
    { int r = tid >> 2, ch = tid & 3;
      int grow = (r >> 4) * 512 + utile * 16 + (r & 15);
      for (int c = 0; c < 8; ++c)
        stageRow(whh0 + (size_t)grow * 512 + c * 64 + ch * 16, &sW[c][r][0], ch);
    }
    const int pb = tid >> 2, uq = tid & 3;
    float cst[4] = {0.f, 0.f, 0.f, 0.f};
    for (int t = 0; t < T; ++t) {
      if (t > 0) wait8(cnt + (size_t)(t - 1) * 128, 4);
      else if (mode == 1) wait8(cnt + (size_t)(2 * T) * 128, 1);   // X0de t=0 ready
      const f16* gpp = G0 + (size_t)(t * 64 + pb) * 2048 + utile * 16 + uq * 4;
      H4 gI, gF, gG, gO;
      gI.v = *(const f16x4*)(gpp);
      gF.v = *(const f16x4*)(gpp + 512);
      gG.v = *(const f16x4*)(gpp + 1024);
      gO.v = *(const f16x4*)(gpp + 1536);
      stageAu((const ull*)h0seq + (size_t)t * 8192, sA, tid);
      __syncthreads();
      f32x4 acc[4] = {};
      kloop64((const f16*)sW, sA, w, m16, g4, acc);
      __syncthreads();
#pragma unroll
      for (int mt = 0; mt < 4; ++mt)
#pragma unroll
        for (int r = 0; r < 4; ++r)
          sG[((size_t)w * 64 + mt * 16 + g4 * 4 + r) * 17 + m16] = acc[mt][r];
      __syncthreads();
      {
        H4 outp;
#pragma unroll
        for (int j = 0; j < 4; ++j) {
          int u = uq * 4 + j;
          float gi = sG[(0 * 64 + pb) * 17 + u] + (float)gI.h[j];
          float gf = sG[(1 * 64 + pb) * 17 + u] + (float)gF.h[j];
          float gg = sG[(2 * 64 + pb) * 17 + u] + (float)gG.h[j];
          float go = sG[(3 * 64 + pb) * 17 + u] + (float)gO.h[j];
          float cn = sigf(gf) * cst[j] + sigf(gi) * tanh_(gg);
          float hn = sigf(go) * tanh_(cn);
          cst[j] = cn;
          outp.h[j] = (f16)hn;
        }
        stU64((ull*)h0seq + (size_t)(t + 1) * 8192 + pb * 128 + utile * 4 + uq, outp.u);
      }
      signalDone(cnt + (size_t)t * 128, bid & 7);
    }
  } else if (bid < 96) {  // ---------- layer 1 (split-phase) ----------
    f16 (*sW2)[8][32][72] = (f16(*)[8][32][72])smem;
    f16 (*sA)[64][72] = (f16(*)[64][72])(smem + 73728);
    float* sG = (float*)(smem + 73728);   // [4][64][9]
    const int utile = bid - 32;
    const int mh = w >> 1, ns = w & 1;
    { int mat = tid >> 7;
      int r = (tid >> 2) & 31, ch = tid & 3;
      int grow = (r >> 3) * 512 + utile * 8 + (r & 7);
      const f16* Wsrc = (mat == 0) ? wih1 : whh1;
      for (int c = 0; c < 8; ++c)
        stageRow(Wsrc + (size_t)grow * 512 + c * 64 + ch * 16, &sW2[mat][c][r][0], ch);
    }
    const int pb = tid >> 2, pup = tid & 3;
    float badd[4][2];
#pragma unroll
    for (int g = 0; g < 4; ++g)
#pragma unroll
      for (int j = 0; j < 2; ++j) {
        int rr = g * 512 + utile * 8 + pup * 2 + j;
        badd[g][j] = bih1[rr] + bhh1[rr];
      }
    float cst[2] = {0.f, 0.f};
    unsigned* line1 = cnt + (size_t)T * 128;
    for (int t = 0; t < T; ++t) {
      wait8(cnt + (size_t)t * 128, 4);
      stageAu((const ull*)h0seq + (size_t)(t + 1) * 8192, sA, tid);   // h0(t)
      if (t > 0) wait8(line1 + (size_t)(t - 1) * 128, 8);
      else       __syncthreads();
      ull rg[8][4];                                                    // h1(t-1) prefetch
      { const ull* s1p = (const ull*)h1seq + (size_t)t * 8192 + (tid >> 2) * 128 + (tid & 3) * 4;
#pragma unroll
        for (int c = 0; c < 8; ++c)
#pragma unroll
          for (int q = 0; q < 4; ++q) rg[c][q] = ldU(s1p + c * 16 + q);
      }
      f32x4 acc[2] = {};
      kloop32(sW2[0], sA, mh, ns, m16, g4, acc);
      __syncthreads();
      { int row = tid >> 2, ch = tid & 3;
#pragma unroll
        for (int c = 0; c < 8; ++c) {
          f16* d = &sA[c][row][0];
          *(ull*)(d +  0 + ch * 4) = rg[c][0];
          *(ull*)(d + 16 + ch * 4) = rg[c][1];
          *(ull*)(d + 32 + ch * 4) = rg[c][2];
          *(ull*)(d + 48 + ch * 4) = rg[c][3];
        }
      }
      __syncthreads();
      kloop32(sW2[1], sA, mh, ns, m16, g4, acc);
      __syncthreads();
      { int nl = ns * 16 + m16;
#pragma unroll
        for (int mt = 0; mt < 2; ++mt)
#pragma unroll
          for (int r = 0; r < 4; ++r) {
            int b = mh * 32 + mt * 16 + g4 * 4 + r;
            sG[((nl >> 3) * 64 + b) * 9 + (nl & 7)] = acc[mt][r];
          }
      }
      __syncthreads();
      {
        H2 outp;
#pragma unroll
        for (int j = 0; j < 2; ++j) {
          int u = pup * 2 + j;
          float gi = sG[(0 * 64 + pb) * 9 + u] + badd[0][j];
          float gf = sG[(1 * 64 + pb) * 9 + u] + badd[1][j];
          float gg = sG[(2 * 64 + pb) * 9 + u] + badd[2][j];
          float go = sG[(3 * 64 + pb) * 9 + u] + badd[3][j];
          float cn = sigf(gf) * cst[j] + sigf(gi) * tanh_(gg);
          float hn = sigf(go) * tanh_(cn);
          cst[j] = cn;
          outp.h[j] = (f16)hn;
        }
        stU32((unsigned*)h1seq + (size_t)(t + 1) * 16384 + pb * 256 + utile * 4 + pup, outp.u);
      }
      signalDone(line1 + (size_t)t * 128, bid & 7);
    }
  } else if (bid < 224) {  // ---------- conv role ----------
    if (mode == 0) {
      convTileC(smem, convBase + bid - 96, cfT, wc9, cb, xemH);
    } else {
      int tile = convBase + bid - 96;
      convTileA(smem, tile, cfT, wc9, cb, xemH);
      signalOne(cnt + 8320 + (tile >> 2) * 16);   // cvb[b] (b = tile>>2 in 32..63)
    }
  } else if (mode == 0) {  // ---------- enc: X0de producer (tt>=1), free-running ----------
    const int rid = bid - 224;
    f16 (*sW)[64][72] = (f16(*)[64][72])smem;
    f16 (*sA)[64][72] = (f16(*)[64][72])(smem + 73728);
    { int r = tid >> 2, ch = tid & 3;
      for (int c = 0; c < 8; ++c)
        stageRow(wihD0 + (size_t)(rid * 64 + r) * 512 + c * 64 + ch * 16, &sW[c][r][0], ch);
    }
    const int e = rid * 64 + w * 16 + m16;
    const float bias_e = bihD0[e] + bhhD0[e];
    const int arow = tid >> 2;
    __syncthreads();
    for (int tt = 1; tt < 32; ++tt) {
      const f16* rowSrc = (tt == 1) ? emb + (size_t)95 * 512
                                    : emb + (size_t)tgt[arow * 30 + tt - 2] * 512;
      stageAp(rowSrc, sA, tid);
      __syncthreads();
      f32x4 acc[4] = {};
      kloop64((const f16*)sW, sA, w, m16, g4, acc);
      __syncthreads();
#pragma unroll
      for (int mt = 0; mt < 4; ++mt)
#pragma unroll
        for (int r = 0; r < 4; ++r)
          X0de[((size_t)tt * 64 + mt * 16 + g4 * 4 + r) * 2048 + e] = (f16)(acc[mt][r] + bias_e);
      __syncthreads();
    }
  } else {  // ---------- dec: X0de t=0 (4 n-tiles) then gemmG chase (8 blocks) ----------
    const int g = bid - 224;
    f16* sWg = (f16*)smem;                               // [8][64][72]
    f16 (*sA)[64][72] = (f16(*)[64][72])(smem + 73728);
    f16 (*sC)[72] = (f16(*)[72])(smem + 73728 + 36864);  // [64][72]
    stageAp(x_t0 + (size_t)(tid >> 2) * 512, sA, tid);
    __syncthreads();
    for (int q = 0; q < 4; ++q) {
      const int rid = g * 4 + q;
      { int r = tid >> 2, ch = tid & 3;
        for (int c = 0; c < 8; ++c)
          stageRow(wihD0 + (size_t)(rid * 64 + r) * 512 + c * 64 + ch * 16,
                   sWg + ((size_t)(c * 64 + r)) * 72, ch);
      }
      __syncthreads();
      f32x4 acc[4] = {};
      kloop64(sWg, sA, w, m16, g4, acc);
      const int e = rid * 64 + w * 16 + m16;
      const float bias_e = bihD0[e] + bhhD0[e];
#pragma unroll
      for (int mt = 0; mt < 4; ++mt)
#pragma unroll
        for (int r = 0; r < 4; ++r)
          X0de[((size_t)(mt * 16 + g4 * 4 + r)) * 2048 + e] = (f16)(acc[mt][r] + bias_e);
      __syncthreads();
    }
    signalDone(cnt + (size_t)(2 * T) * 128, g);
    { int r = tid >> 2, ch = tid & 3;
      for (int c = 0; c < 8; ++c)
        stageRow(awh + (size_t)(g * 64 + r) * 512 + c * 64 + ch * 16,
                 sWg + ((size_t)(c * 64 + r)) * 72, ch);
    }
    const int e = g * 64 + w * 16 + m16;
    const float gb = gbias[e];
    __syncthreads();
    unsigned* line1 = cnt + (size_t)T * 128;
    for (int t = 0; t < T; ++t) {
      wait8(line1 + (size_t)t * 128, 8);
      stageAu((const ull*)h1seq + (size_t)(t + 1) * 8192, sA, tid);
      __syncthreads();
      f32x4 acc[4] = {};
      kloop64(sWg, sA, w, m16, g4, acc);
      __syncthreads();
      // packed agent epilogue (same-kernel consumers read via ldU)
#pragma unroll
      for (int mt = 0; mt < 4; ++mt)
#pragma unroll
        for (int r = 0; r < 4; ++r)
          sC[mt * 16 + g4 * 4 + r][w * 16 + m16] = (f16)(acc[mt][r] + gb);
      __syncthreads();
#pragma unroll
      for (int k = 0; k < 4; ++k) {
        int id = tid + k * 256;          // 1024 chunks: 64 rows x 16
        int row = id >> 4, chk = id & 15;
        H4 pk; pk.v = *(const f16x4*)&sC[row][chk * 4];
        stU64((ull*)gAll + (size_t)(t * 64 + row) * 128 + g * 16 + chk, pk.u);
      }
      __syncthreads();
    }
    signalOne(cnt + 9344);   // gemmG done (drains agent stores)
  }

  if (mode == 0) return;

  // =================== dec post-pass tail ===================
  __syncthreads();
  unsigned* cvb = cnt + 8320;
  unsigned* gGd = cnt + 9344;
  unsigned* scb = cnt + 9360;
  unsigned* smd = cnt + 10384;
  unsigned* lgd = cnt + 10448;

  // ---- score tasks: (tile,b), 768 total ----
  {
    f16 (*sX)[512] = (f16(*)[512])smem;   // [20][512]
    ull* sXu = (ull*)smem;
    float w8[8];
    { const float4* wp = (const float4*)(wv + lane * 8);
      float4 wa = wp[0], wb2 = wp[1];
      w8[0] = wa.x; w8[1] = wa.y; w8[2] = wa.z; w8[3] = wa.w;
      w8[4] = wb2.x; w8[5] = wb2.y; w8[6] = wb2.z; w8[7] = wb2.w; }
    for (int task = bid; task < 768; task += 232) {
      int b = task / 12, tile = task - b * 12;
      if (tid == 0 && b >= 32) {
        while (ldF(cvb + b * 16) < 4u) __builtin_amdgcn_s_sleep(2);
      } else if (tid == 1) {
        while (ldF(gGd) < 8u) __builtin_amdgcn_s_sleep(2);
      }
      __syncthreads();
      for (int i = tid; i < 2560; i += 256)
        sXu[i] = ldU((const ull*)xemH + (size_t)(b * 240 + tile * 20 + (i >> 7)) * 128 + (i & 127));
      __syncthreads();
      for (int t = 0; t < 32; ++t) {
        const ull* gp = (const ull*)gAll + (size_t)(t * 64 + b) * 128 + lane * 2;
        H4 ga, gb4; ga.u = ldU(gp); gb4.u = ldU(gp + 1);
        float g8[8];
#pragma unroll
        for (int j = 0; j < 4; ++j) { g8[j] = (float)ga.h[j]; g8[4 + j] = (float)gb4.h[j]; }
#pragma unroll
        for (int i = 0; i < 5; ++i) {
          int rr = i * 4 + w;
          f16x8 xv = *(const f16x8*)&sX[rr][lane * 8];
          float s = 0.f;
#pragma unroll
          for (int j = 0; j < 8; ++j) s += tanh_((float)xv[j] + g8[j]) * w8[j];
#pragma unroll
          for (int m = 32; m; m >>= 1) s += __shfl_xor(s, m);
          if (lane == 0) {
            U32F u; u.f = s;
            stU32((unsigned*)escAll + (size_t)(t * 64 + b) * 240 + tile * 20 + rr, u.u);
          }
        }
      }
      signalOne(scb + b * 16);
      __syncthreads();
    }
  }

  // ---- smctx tasks: (tq,b), 256 total ----
  {
    float* aAl = (float*)smem;   // [8][240]
    for (int task = bid; task < 256; task += 232) {
      int tq = task >> 6, b = task & 63;
      if (tid == 0)
        while (ldF(scb + b * 16) < 12u) __builtin_amdgcn_s_sleep(2);
      __syncthreads();
      for (int half = 0; half < 2; ++half) {
        int tt = w + half * 4;
        int t = tq * 8 + tt;
        const unsigned* er = (const unsigned*)escAll + (size_t)(t * 64 + b) * 240;
        float v[4]; float mx = -1e30f;
#pragma unroll
        for (int q = 0; q < 4; ++q) {
          int p = lane + q * 64;
          if (p < 240) { U32F u; u.u = ldF(er + p); v[q] = u.f; } else v[q] = -1e30f;
          mx = fmaxf(mx, v[q]);
        }
#pragma unroll
        for (int m = 32; m; m >>= 1) mx = fmaxf(mx, __shfl_xor(mx, m));
        float sum = 0.f;
#pragma unroll
        for (int q = 0; q < 4; ++q) { v[q] = __expf(v[q] - mx); sum += v[q]; }
#pragma unroll
        for (int m = 32; m; m >>= 1) sum += __shfl_xor(sum, m);
        float inv = 1.f / sum;
#pragma unroll
        for (int q = 0; q < 4; ++q) {
          int p = lane + q * 64;
          if (p < 240) aAl[tt * 240 + p] = v[q] * inv;
        }
      }
      __syncthreads();
      float acc2[8][2] = {};
      const f16* cbp = cfT + (size_t)b * 240 * 512;
      for (int p = 0; p < 240; ++p) {
        H2 cw; cw.u = *(const unsigned*)(cbp + (size_t)p * 512 + tid * 2);
        float c0 = (float)cw.h[0], c1 = (float)cw.h[1];
#pragma unroll
        for (int tt = 0; tt < 8; ++tt) {
          float a = aAl[tt * 240 + p];
          acc2[tt][0] += a * c0;
          acc2[tt][1] += a * c1;
        }
      }
#pragma unroll
      for (int tt = 0; tt < 8; ++tt) {
        int t = tq * 8 + tt;
        size_t r = (size_t)(t * 64 + b);
        H2 o; o.h[0] = (f16)acc2[tt][0]; o.h[1] = (f16)acc2[tt][1];
        stU32((unsigned*)ctxAll + r * 512 + 256 + tid, o.u);
        unsigned hv = ldF((const unsigned*)h1seq + (size_t)(t + 1) * 16384 + b * 256 + tid);
        stU32((unsigned*)ctxAll + r * 512 + tid, hv);
      }
      signalOne(smd + tq * 16);
      __syncthreads();
    }
  }

  // ---- logit tasks: t, 32 total (blocks 0..31) ----
  if (bid < 32) {
    int t = bid;
    if (tid == 0)
      while (ldF(smd + (t >> 3) * 16) < 64u) __builtin_amdgcn_s_sleep(2);
    __syncthreads();
    f16 (*At)[72] = (f16(*)[72])smem;                   // [64][72]
    f16 (*Bt)[64][72] = (f16(*)[64][72])(smem + 9216);  // [2][64][72]
    float (*sL)[100] = (float(*)[100])(smem + 46080);   // [64][100]
    const int g = tid >> 6;
    f32x4 acc[2][4] = {};
    for (int k0 = 0; k0 < 1024; k0 += 64) {
      __syncthreads();
      { int row = tid >> 2, ch = tid & 3;
        const ull* rb = (const ull*)ctxAll + (size_t)(t * 64 + row) * 256 + (k0 >> 2) + ch * 4;
        ull d0 = ldU(rb), d1 = ldU(rb + 1), d2 = ldU(rb + 2), d3 = ldU(rb + 3);
        f16* dr = &At[row][0];
        *(ull*)(dr +  0 + ch * 4) = d0;
        *(ull*)(dr + 16 + ch * 4) = d1;
        *(ull*)(dr + 32 + ch * 4) = d2;
        *(ull*)(dr + 48 + ch * 4) = d3;
        stageRow(outwH + (size_t)row * 1024 + k0 + ch * 16, &Bt[0][row][0], ch);
        stageRow(outwH + (size_t)(64 + row) * 1024 + k0 + ch * 16, &Bt[1][row][0], ch);
      }
      __syncthreads();
#pragma unroll
      for (int n2 = 0; n2 < 2; ++n2)
#pragma unroll
        for (int half = 0; half < 2; ++half) {
          f16x8 bf = *(const f16x8*)&Bt[n2][g * 16 + m16][g4 * 16 + half * 8];
          f16x4 bl = lo4(bf), bh = hi4(bf);
#pragma unroll
          for (int mt = 0; mt < 4; ++mt) {
            f16x8 af = *(const f16x8*)&At[mt * 16 + m16][g4 * 16 + half * 8];
            acc[n2][mt] = mfma16(lo4(af), bl, acc[n2][mt]);
            acc[n2][mt] = mfma16(hi4(af), bh, acc[n2][mt]);
          }
        }
    }
    __syncthreads();
#pragma unroll
    for (int n2 = 0; n2 < 2; ++n2) {
      int e = n2 * 64 + g * 16 + m16;
      if (e < 96) {
        float be = outb[e];
#pragma unroll
        for (int mt = 0; mt < 4; ++mt)
#pragma unroll
          for (int r = 0; r < 4; ++r)
            sL[mt * 16 + g4 * 4 + r][e] = acc[n2][mt][r] + be;
      }
    }
    __syncthreads();
    if (tid < 64) {
      int b = tid;
      int jj = 31;
      for (int q = 1; q <= 30; ++q)
        if (tgt[b * 30 + q - 1] == 0) { jj = q; break; }
      int tok = (t == 0 || t == 31) ? 0 : tgt[b * 30 + t - 1];
      if (t == jj) tok = 95;
      float val = 0.f;
      if (tok != 0) {
        float mx = -1e30f;
        for (int j = 0; j < 96; ++j) mx = fmaxf(mx, sL[b][j]);
        float s = 0.f;
        for (int j = 0; j < 96; ++j) s += __expf(sL[b][j] - mx);
        val = mx + __logf(s) - sL[b][tok];
      }
      U32F o; o.f = val;
      stU32((unsigned*)nllb + t * 64 + b, o.u);
    }
    signalOne(lgd);
  }

  // ---- loss: block 0 ----
  if (bid == 0) {
    if (tid == 0)
      while (ldF(lgd) < 32u) __builtin_amdgcn_s_sleep(2);
    __syncthreads();
    float* sa = (float*)smem;
    float* sb = sa + 256;
    float a = 0.f, m = 0.f;
    for (int i = tid; i < 2048; i += 256) {
      U32F u; u.u = ldF((const unsigned*)nllb + i);
      a += u.f;
    }
    if (tid < 64) {
      int b = tid;
      int jj = 31;
      for (int q = 1; q <= 30; ++q)
        if (tgt[b * 30 + q - 1] == 0) { jj = q; break; }
      int cntk = 0;
      for (int t = 1; t <= 30; ++t) {
        int v = tgt[b * 30 + t - 1];
        if (t == jj) v = 95;
        if (v != 0) ++cntk;
      }
      if (jj == 31) ++cntk;
      m = (float)cntk;
    }
    sa[tid] = a; sb[tid] = m; __syncthreads();
    for (int s = 128; s; s >>= 1) {
      if (tid < s) { sa[tid] += sa[tid + s]; sb[tid] += sb[tid + s]; }
      __syncthreads();
    }
    if (tid == 0) out[0] = sa[0] / sb[0];
  }
}

// ---------------- host ----------------

extern "C" void kernel_launch(void* const* d_in, const int* in_sizes, int n_in,
                              void* d_out, int out_size, void* d_ws, size_t ws_size,
                              hipStream_t stream) {
  (void)in_sizes; (void)n_in; (void)out_size; (void)ws_size;
  const float* conv_f = (const float*)d_in[0];
  const int*   target = (const int*)d_in[1];
  const float* wih_en = (const float*)d_in[2];
  const float* whh_en = (const float*)d_in[3];
  const float* bih_en = (const float*)d_in[4];
  const float* bhh_en = (const float*)d_in[5];
  const float* embed  = (const float*)d_in[6];
  const float* wih_de = (const float*)d_in[7];
  const float* whh_de = (const float*)d_in[8];
  const float* bih_de = (const float*)d_in[9];
  const float* bhh_de = (const float*)d_in[10];
  const float* att_wh = (const float*)d_in[11];
  const float* att_bh = (const float*)d_in[12];
  const float* att_cw = (const float*)d_in[13];
  const float* att_cb = (const float*)d_in[14];
  const float* att_wv = (const float*)d_in[15];
  const float* out_w  = (const float*)d_in[17];
  const float* out_b  = (const float*)d_in[18];
  float* out = (float*)d_out;

  size_t o = 0;
  char* base = (char*)d_ws;
  auto take = [&](size_t bytes) -> void* {
    void* p = base + o;
    o += (bytes + 255) & ~(size_t)255;
    return p;
  };
  const size_t WSZ = (size_t)2048 * 512;
  f16* wihEn = (f16*)take(2 * WSZ * 2);
  f16* whhEn = (f16*)take(2 * WSZ * 2);
  f16* wihDe = (f16*)take(2 * WSZ * 2);
  f16* whhDe = (f16*)take(2 * WSZ * 2);
  f16* awh   = (f16*)take((size_t)512 * 512 * 2);
  f16* emb   = (f16*)take((size_t)96 * 512 * 2);
  f16* wc9   = (f16*)take((size_t)512 * 4608 * 2);
  f16* cfT   = (f16*)take((size_t)64 * 240 * 512 * 2);
  f16* xseq  = (f16*)take((size_t)40 * 64 * 512 * 2);
  f16* xemH  = (f16*)take((size_t)64 * 240 * 512 * 2);
  f16* outwH = (f16*)take((size_t)128 * 1024 * 2);
  f16* X0en  = (f16*)take((size_t)2560 * 2048 * 2);
  f16* X0de  = (f16*)take((size_t)2048 * 2048 * 2);
  f16* h0seqE = (f16*)take((size_t)41 * HB * 2);
  f16* h1seqE = (f16*)take((size_t)41 * HB * 2);
  f16* h0seqD = (f16*)take((size_t)33 * HB * 2);
  f16* h1seqD = (f16*)take((size_t)33 * HB * 2);
  f16* gAll   = (f16*)take((size_t)2048 * 512 * 2);
  float* nllb = (float*)take((size_t)2048 * 4);
  unsigned* cntE = (unsigned*)take(65536);
  unsigned* cntD = (unsigned*)take(65536);
  // aliases onto dead precompute buffers
  float* escAll = (float*)X0en;                          // 2048*240*4
  f16*   ctxAll = (f16*)((char*)X0en + 4194304);         // 2048*1024*2 (X0en is 10.5MB)

  // prologue: cfmx + merged prep (wc9/convW/convS/zero)
  k_cfmx<<<dim3(8, 64), 256, 0, stream>>>(conv_f, cfT, xseq);
  k_prep<<<9488, 256, 0, stream>>>(att_cw, wc9,
                                   wih_en, whh_en, wih_de, whh_de,
                                   wihEn, whhEn, wihDe, whhDe,
                                   att_wh, embed, out_w, awh, emb, outwH,
                                   (unsigned*)h0seqE, (unsigned*)h1seqE,
                                   (unsigned*)h0seqD, (unsigned*)h1seqD, cntE, cntD);

  // encoder X0 then persistent encoder (+ conv 0..127 + X0de tt>=1 producers)
  k_gemmX<<<dim3(40, 32), 256, 0, stream>>>(xseq, wihEn, bih_en, bhh_en, X0en);
  k_lstm<<<256, 256, 0, stream>>>(40, 0, X0en, whhEn, wihEn + WSZ, whhEn + WSZ,
                                  bih_en + 2048, bhh_en + 2048, h0seqE, h1seqE, cntE,
                                  cfT, wc9, att_cb, xemH, 0,
                                  X0de, wihDe, bih_de, bhh_de, emb, target,
                                  nullptr, nullptr, nullptr, nullptr,
                                  att_wv, outwH, out_b, escAll, ctxAll, nllb, out);

  // persistent decoder (+ conv 128..255 + X0de t=0 + gemmG) + full post-pass tail
  k_lstm<<<232, 256, 0, stream>>>(32, 1, X0de, whhDe, wihDe + WSZ, whhDe + WSZ,
                                  bih_de + 2048, bhh_de + 2048, h0seqD, h1seqD, cntD,
                                  cfT, wc9, att_cb, xemH, 128,
                                  X0de, wihDe, bih_de, bhh_de, emb, target,
                                  h1seqE + (size_t)40 * HB,
                                  awh, att_bh, gAll,
                                  att_wv, outwH, out_b, escAll, ctxAll, nllb, out);
}

// Round 15
// 769.144 us; speedup vs baseline: 1.3002x; 1.3002x over previous
//
#include <hip/hip_runtime.h>

typedef __fp16 f16;
typedef __fp16 f16x4 __attribute__((ext_vector_type(4)));
typedef __fp16 f16x8 __attribute__((ext_vector_type(8)));
typedef float  f32x4 __attribute__((ext_vector_type(4)));
typedef unsigned long long ull;

#define DEV static __device__ __forceinline__

DEV f32x4 mfma16(f16x4 a, f16x4 b, f32x4 c) {
  return __builtin_amdgcn_mfma_f32_16x16x16f16(a, b, c, 0, 0, 0);
}
DEV f16x4 lo4(f16x8 v) { return __builtin_shufflevector(v, v, 0, 1, 2, 3); }
DEV f16x4 hi4(f16x8 v) { return __builtin_shufflevector(v, v, 4, 5, 6, 7); }
DEV float sigf(float x) { return 1.f / (1.f + __expf(-x)); }
DEV float tanh_(float x) { float e = __expf(2.f * x); return 1.f - 2.f / (e + 1.f); }

union U8 { float4 f4; float2 f2[2]; };
union H2 { unsigned u; f16 h[2]; };
union H4 { ull u; f16 h[4]; f16x4 v; };

#define HB 32768   // f16 elements in a [64][512] buffer

// ---- agent-coherent (L2-bypassing) helpers ----
DEV ull ldU(const ull* p) {
  return __hip_atomic_load(p, __ATOMIC_RELAXED, __HIP_MEMORY_SCOPE_AGENT);
}
DEV unsigned ldF(const unsigned* p) {
  return __hip_atomic_load(p, __ATOMIC_RELAXED, __HIP_MEMORY_SCOPE_AGENT);
}
DEV void stU32(unsigned* p, unsigned v) {
  __hip_atomic_store(p, v, __ATOMIC_RELAXED, __HIP_MEMORY_SCOPE_AGENT);
}
DEV void stU64(ull* p, ull v) {
  __hip_atomic_store(p, v, __ATOMIC_RELAXED, __HIP_MEMORY_SCOPE_AGENT);
}

// 8-slot line poll (lanes 0-7), then block barrier
DEV void wait8(const unsigned* line, unsigned tgt) {
  if (threadIdx.x < 8)
    while (ldF(line + threadIdx.x * 16) < tgt) {}
  __syncthreads();
}

DEV void signalDone(unsigned* line, int slot) {
  asm volatile("s_waitcnt vmcnt(0)" ::: "memory");  // drain h stores (per wave)
  __syncthreads();
  if (threadIdx.x == 0)
    __hip_atomic_fetch_add(line + slot * 16, 1u, __ATOMIC_RELAXED, __HIP_MEMORY_SCOPE_AGENT);
}

// k-permuted staging of 16 f16 (cached path)
DEV void stageRow(const f16* __restrict__ s, f16* __restrict__ dstRow, int ch) {
  U8 u0, u1;
  u0.f4 = *(const float4*)s;
  u1.f4 = *(const float4*)(s + 8);
  *(float2*)(dstRow +  0 + ch * 4) = u0.f2[0];
  *(float2*)(dstRow + 16 + ch * 4) = u0.f2[1];
  *(float2*)(dstRow + 32 + ch * 4) = u1.f2[0];
  *(float2*)(dstRow + 48 + ch * 4) = u1.f2[1];
}

// cached stage with per-row source pointer (row = tid>>2)
DEV void stageAp(const f16* __restrict__ rowSrc, f16 (*A)[64][72], int tid) {
  int ch = tid & 3;
  const f16* s = rowSrc + ch * 16;
#pragma unroll
  for (int c = 0; c < 8; ++c)
    stageRow(s + c * 64, &A[c][tid >> 2][0], ch);
}

// coherent stage of [64][512] A into sA[8][64][72]
DEV void stageAu(const ull* __restrict__ srcU, f16 (*A)[64][72], int tid) {
  int row = tid >> 2, ch = tid & 3;
  const ull* s = srcU + row * 128 + ch * 4;
#pragma unroll
  for (int c = 0; c < 8; ++c) {
    ull d0 = ldU(s + c * 16 + 0);
    ull d1 = ldU(s + c * 16 + 1);
    ull d2 = ldU(s + c * 16 + 2);
    ull d3 = ldU(s + c * 16 + 3);
    f16* d = &A[c][row][0];
    *(ull*)(d +  0 + ch * 4) = d0;
    *(ull*)(d + 16 + ch * 4) = d1;
    *(ull*)(d + 32 + ch * 4) = d2;
    *(ull*)(d + 48 + ch * 4) = d3;
  }
}

// 64x32 output tile: wave (mh,ns); acc[2]
DEV void kloop32(const f16 (*Wt)[32][72], const f16 (*A)[64][72],
                 int mh, int ns, int m16, int g4, f32x4 acc[2]) {
#pragma unroll
  for (int c = 0; c < 8; ++c) {
#pragma unroll
    for (int half = 0; half < 2; ++half) {
      f16x8 bf = *(const f16x8*)&Wt[c][ns * 16 + m16][g4 * 16 + half * 8];
      f16x4 bl = lo4(bf), bh = hi4(bf);
#pragma unroll
      for (int mt = 0; mt < 2; ++mt) {
        f16x8 af = *(const f16x8*)&A[c][mh * 32 + mt * 16 + m16][g4 * 16 + half * 8];
        acc[mt] = mfma16(lo4(af), bl, acc[mt]);
        acc[mt] = mfma16(hi4(af), bh, acc[mt]);
      }
    }
  }
}

// 64x64 output tile: wave = n-16-group; acc[4]
DEV void kloop64(const f16* Wg, const f16 (*A)[64][72],
                 int nsG, int m16, int g4, f32x4 acc[4]) {
#pragma unroll
  for (int c = 0; c < 8; ++c) {
#pragma unroll
    for (int half = 0; half < 2; ++half) {
      f16x8 bf = *(const f16x8*)&Wg[((size_t)(c * 64 + nsG * 16 + m16)) * 72 + g4 * 16 + half * 8];
      f16x4 bl = lo4(bf), bh = hi4(bf);
#pragma unroll
      for (int mt = 0; mt < 4; ++mt) {
        f16x8 af = *(const f16x8*)&A[c][mt * 16 + m16][g4 * 16 + half * 8];
        acc[mt] = mfma16(lo4(af), bl, acc[mt]);
        acc[mt] = mfma16(hi4(af), bh, acc[mt]);
      }
    }
  }
}

// ---------------- conv tile (role inside k_lstm); cached epilogue ----------------
DEV void convTile(char* smem, int tile, const f16* __restrict__ cfT,
                  const f16* __restrict__ wc9, const float* __restrict__ cb,
                  f16* __restrict__ xemH) {
  f16 (*At)[40] = (f16(*)[40])smem;                 // [240][40]
  f16 (*Bt)[40] = (f16(*)[40])(smem + 19200);       // [128][40]
  const int t = threadIdx.x, lane = t & 63, w = t >> 6;
  const int b = tile >> 2, eb = (tile & 3) * 128;
  const int m16 = lane & 15, g4 = lane >> 4;
  f32x4 acc[15][2] = {};

  for (int kr = 0; kr < 9; ++kr) {
    int dh = kr / 3 - 1, dw = kr % 3 - 1;
    for (int f0 = 0; f0 < 512; f0 += 32) {
      __syncthreads();
      if (t < 240) {
        int hh = t / 40 + dh, ww = t % 40 + dw;
        if (hh >= 0 && hh < 6 && ww >= 0 && ww < 40) {
          const f16* s = cfT + ((size_t)(b * 240 + hh * 40 + ww) * 512 + f0);
          U8 u0, u1, u2, u3;
          u0.f4 = *(const float4*)s;        u1.f4 = *(const float4*)(s + 8);
          u2.f4 = *(const float4*)(s + 16); u3.f4 = *(const float4*)(s + 24);
          *(float2*)&At[t][ 0] = u0.f2[0];
          *(float2*)&At[t][ 8] = u0.f2[1];
          *(float2*)&At[t][16] = u1.f2[0];
          *(float2*)&At[t][24] = u1.f2[1];
          *(float2*)&At[t][ 4] = u2.f2[0];
          *(float2*)&At[t][12] = u2.f2[1];
          *(float2*)&At[t][20] = u3.f2[0];
          *(float2*)&At[t][28] = u3.f2[1];
        } else {
          float2 z = make_float2(0.f, 0.f);
          *(float2*)&At[t][ 0] = z; *(float2*)&At[t][ 8] = z;
          *(float2*)&At[t][16] = z; *(float2*)&At[t][24] = z;
          *(float2*)&At[t][ 4] = z; *(float2*)&At[t][12] = z;
          *(float2*)&At[t][20] = z; *(float2*)&At[t][28] = z;
        }
      }
      {
        int n = t >> 1, ch = t & 1;
        const f16* s = wc9 + (size_t)(eb + n) * 4608 + kr * 512 + f0 + ch * 16;
        U8 u0, u1;
        u0.f4 = *(const float4*)s; u1.f4 = *(const float4*)(s + 8);
        *(float2*)&Bt[n][ 0 + ch * 4] = u0.f2[0];
        *(float2*)&Bt[n][ 8 + ch * 4] = u0.f2[1];
        *(float2*)&Bt[n][16 + ch * 4] = u1.f2[0];
        *(float2*)&Bt[n][24 + ch * 4] = u1.f2[1];
      }
      __syncthreads();
      f16x8 b0 = *(const f16x8*)&Bt[w * 32 + m16][g4 * 8];
      f16x8 b1v = *(const f16x8*)&Bt[w * 32 + 16 + m16][g4 * 8];
      f16x4 b0l = lo4(b0), b0h = hi4(b0), b1l = lo4(b1v), b1h = hi4(b1v);
#pragma unroll
      for (int mt = 0; mt < 15; ++mt) {
        f16x8 af = *(const f16x8*)&At[mt * 16 + m16][g4 * 8];
        f16x4 al = lo4(af), ah = hi4(af);
        acc[mt][0] = mfma16(al, b0l, acc[mt][0]);
        acc[mt][1] = mfma16(al, b1l, acc[mt][1]);
        acc[mt][0] = mfma16(ah, b0h, acc[mt][0]);
        acc[mt][1] = mfma16(ah, b1h, acc[mt][1]);
      }
    }
  }
#pragma unroll
  for (int nt = 0; nt < 2; ++nt) {
    int e = eb + w * 32 + nt * 16 + m16;
    float bias = cb[e];
#pragma unroll
    for (int mt = 0; mt < 15; ++mt)
#pragma unroll
      for (int r = 0; r < 4; ++r) {
        int p = mt * 16 + g4 * 4 + r;
        xemH[((size_t)(b * 240 + p)) * 512 + e] = (f16)(acc[mt][nt][r] + bias);
      }
  }
}

// ---------------- merged prologue: wc9 + convW + convS + zero ----------------
__global__ __launch_bounds__(256) void k_prep(
    const float* __restrict__ att_cw, f16* __restrict__ wc9,
    const float* __restrict__ s0, const float* __restrict__ s1,
    const float* __restrict__ s2, const float* __restrict__ s3,
    f16* __restrict__ d0, f16* __restrict__ d1,
    f16* __restrict__ d2, f16* __restrict__ d3,
    const float* __restrict__ awhS, const float* __restrict__ embS,
    const float* __restrict__ outwS,
    f16* __restrict__ awhD, f16* __restrict__ embD, f16* __restrict__ outwD,
    unsigned* __restrict__ z0, unsigned* __restrict__ z1, unsigned* __restrict__ z2,
    unsigned* __restrict__ z3, unsigned* __restrict__ z4, unsigned* __restrict__ z5)
{
  const int bid = blockIdx.x, tid = threadIdx.x;
  if (bid < 512) {                       // wc9 transpose (one e row per block)
    __shared__ float s[4608];
    const int e = bid;
    for (int i = tid; i < 4608; i += 256) s[i] = att_cw[(size_t)e * 4608 + i];
    __syncthreads();
    for (int j = tid; j < 4608; j += 256) {
      int rr = j >> 9, f = j & 511;
      wc9[(size_t)e * 4608 + j] = (f16)s[f * 9 + rr];
    }
  } else if (bid < 8704) {               // convW: 4 big LSTM weight blocks
    int i = (bid - 512) * 256 + tid;
    int sel = i >> 19, j = i & 524287;
    const float* s = sel == 0 ? s0 : sel == 1 ? s1 : sel == 2 ? s2 : s3;
    f16* d = sel == 0 ? d0 : sel == 1 ? d1 : sel == 2 ? d2 : d3;
    float4 v = ((const float4*)s)[j];
    f16x4 o = { (f16)v.x, (f16)v.y, (f16)v.z, (f16)v.w };
    *(f16x4*)(d + (size_t)j * 4) = o;
  } else if (bid < 9104) {               // convS: awh, emb, outw
    int i = (bid - 8704) * 256 + tid;
    const float* s; f16* d; int j;
    if (i < 65536) { s = awhS; d = awhD; j = i; }
    else if (i < 65536 + 12288) { s = embS; d = embD; j = i - 65536; }
    else if (i < 65536 + 12288 + 24576) { s = outwS; d = outwD; j = i - 65536 - 12288; }
    else return;
    float4 v = ((const float4*)s)[j];
    f16x4 o = { (f16)v.x, (f16)v.y, (f16)v.z, (f16)v.w };
    *(f16x4*)(d + (size_t)j * 4) = o;
  } else {                               // zero 6 x 16384-dword regions
    int i = (bid - 9104) * 256 + tid;
    int sel = i >> 14, j = i & 16383;
    unsigned* p = sel == 0 ? z0 : sel == 1 ? z1 : sel == 2 ? z2 :
                  sel == 3 ? z3 : sel == 4 ? z4 : z5;
    p[j] = 0;
  }
}

__global__ __launch_bounds__(256) void k_cfmx(
    const float* __restrict__ cf, f16* __restrict__ cfT, f16* __restrict__ xseq)
{
  __shared__ float sT[64][244];
  const int tid = threadIdx.x;
  const int f0 = blockIdx.x * 64, b = blockIdx.y;
  const float* src = cf + ((size_t)b * 512 + f0) * 240;
  for (int i = tid; i < 3840; i += 256) {
    float4 v = ((const float4*)src)[i];
    int fl = i / 60, pc = (i % 60) * 4;
    sT[fl][pc] = v.x; sT[fl][pc + 1] = v.y; sT[fl][pc + 2] = v.z; sT[fl][pc + 3] = v.w;
  }
  __syncthreads();
  if (tid < 240) {
    int p = tid;
    f16* drow = cfT + ((size_t)b * 240 + p) * 512 + f0;
#pragma unroll
    for (int j = 0; j < 8; ++j) {
      f16x8 o;
#pragma unroll
      for (int k = 0; k < 8; ++k) o[k] = (f16)sT[j * 8 + k][p];
      *(f16x8*)(drow + j * 8) = o;
    }
  }
  {
    int fl = tid >> 2, wq = tid & 3;
#pragma unroll
    for (int wi = 0; wi < 10; ++wi) {
      int w = wq * 10 + wi;
      float m = sT[fl][w];
#pragma unroll
      for (int h = 1; h < 6; ++h) m = fmaxf(m, sT[fl][h * 40 + w]);
      xseq[((size_t)w * 64 + b) * 512 + f0 + fl] = (f16)m;
    }
  }
}

// ---------------- batched X0 GEMM (encoder) ----------------
__global__ __launch_bounds__(256) void k_gemmX(
    const f16* __restrict__ A, const f16* __restrict__ W,
    const float* __restrict__ b1, const float* __restrict__ b2,
    f16* __restrict__ C)
{
  __shared__ f16 At[64][72];
  __shared__ f16 Bt[64][72];
  const int t = threadIdx.x, lane = t & 63, g = t >> 6;
  f32x4 acc[4] = {};
  const int m16 = lane & 15, g4 = lane >> 4;
  const size_t arow0 = (size_t)blockIdx.x * 64;

  for (int k0 = 0; k0 < 512; k0 += 64) {
    __syncthreads();
    { int row = t >> 2, ch = t & 3;
      stageRow(A + (arow0 + row) * 512 + k0 + ch * 16, &At[row][0], ch); }
    { int row = t >> 2, ch = t & 3;
      stageRow(W + ((size_t)blockIdx.y * 64 + row) * 512 + k0 + ch * 16, &Bt[row][0], ch); }
    __syncthreads();
#pragma unroll
    for (int half = 0; half < 2; ++half) {
      f16x8 bf = *(const f16x8*)&Bt[g * 16 + m16][g4 * 16 + half * 8];
      f16x4 bl = lo4(bf), bh = hi4(bf);
#pragma unroll
      for (int mt = 0; mt < 4; ++mt) {
        f16x8 af = *(const f16x8*)&At[mt * 16 + m16][g4 * 16 + half * 8];
        acc[mt] = mfma16(lo4(af), bl, acc[mt]);
        acc[mt] = mfma16(hi4(af), bh, acc[mt]);
      }
    }
  }
  int e = blockIdx.y * 64 + g * 16 + m16;
  float bias = b1[e] + b2[e];
#pragma unroll
  for (int mt = 0; mt < 4; ++mt)
#pragma unroll
    for (int r = 0; r < 4; ++r)
      C[(arow0 + mt * 16 + g4 * 4 + r) * 2048 + e] = (f16)(acc[mt][r] + bias);
}

// ---------------- persistent 2-layer LSTM + roles ----------------
// mode 0 (enc, 256 blocks): [0,32)L0 [32,96)L1 [96,224)conv(0..127) [224,256)X0de(tt>=1)
// mode 1 (dec, 232 blocks): [0,32)L0 [32,96)L1 [96,224)conv(128..255) [224,232)X0t0+gemmG
// cnt: lineL0[t] at t*128 (8 slots, tgt 4), lineL1[t] at (T+t)*128 (tgt 8),
//      dec lineX0 at 2T*128 (8 slots, tgt 1)
__global__ __launch_bounds__(256, 1) void k_lstm(
    int T, int mode,
    const f16* __restrict__ G0, const f16* __restrict__ whh0,
    const f16* __restrict__ wih1, const f16* __restrict__ whh1,
    const float* __restrict__ bih1, const float* __restrict__ bhh1,
    f16* __restrict__ h0seq, f16* __restrict__ h1seq,
    unsigned* __restrict__ cnt,
    const f16* __restrict__ cfT, const f16* __restrict__ wc9,
    const float* __restrict__ cb, f16* __restrict__ xemH, int convBase,
    f16* __restrict__ X0de, const f16* __restrict__ wihD0,
    const float* __restrict__ bihD0, const float* __restrict__ bhhD0,
    const f16* __restrict__ emb, const int* __restrict__ tgt,
    const f16* __restrict__ x_t0,
    const f16* __restrict__ awh, const float* __restrict__ gbias, f16* __restrict__ gAll)
{
  __shared__ __align__(16) char smem[147456];
  const int tid = threadIdx.x, lane = tid & 63, w = tid >> 6;
  const int m16 = lane & 15, g4 = lane >> 4;
  const int bid = blockIdx.x;

  if (bid < 32) {  // ---------- layer 0 ----------
    f16 (*sW)[64][72] = (f16(*)[64][72])smem;
    f16 (*sA)[64][72] = (f16(*)[64][72])(smem + 73728);
    float* sG = (float*)(smem + 73728);   // [4][64][17]
    const int utile = bid;
    { int r = tid >> 2, ch = tid & 3;
      int grow = (r >> 4) * 512 + utile * 16 + (r & 15);
      for (int c = 0; c < 8; ++c)
        stageRow(whh0 + (size_t)grow * 512 + c * 64 + ch * 16, &sW[c][r][0], ch);
    }
    const int pb = tid >> 2, uq = tid & 3;
    float cst[4] = {0.f, 0.f, 0.f, 0.f};
    for (int t = 0; t < T; ++t) {
      if (t > 0) wait8(cnt + (size_t)(t - 1) * 128, 4);
      else if (mode == 1) wait8(cnt + (size_t)(2 * T) * 128, 1);   // X0de t=0 ready
      const f16* gpp = G0 + (size_t)(t * 64 + pb) * 2048 + utile * 16 + uq * 4;
      H4 gI, gF, gG, gO;
      gI.v = *(const f16x4*)(gpp);
      gF.v = *(const f16x4*)(gpp + 512);
      gG.v = *(const f16x4*)(gpp + 1024);
      gO.v = *(const f16x4*)(gpp + 1536);
      stageAu((const ull*)h0seq + (size_t)t * 8192, sA, tid);
      __syncthreads();
      f32x4 acc[4] = {};
      kloop64((const f16*)sW, sA, w, m16, g4, acc);
      __syncthreads();
#pragma unroll
      for (int mt = 0; mt < 4; ++mt)
#pragma unroll
        for (int r = 0; r < 4; ++r)
          sG[((size_t)w * 64 + mt * 16 + g4 * 4 + r) * 17 + m16] = acc[mt][r];
      __syncthreads();
      {
        H4 outp;
#pragma unroll
        for (int j = 0; j < 4; ++j) {
          int u = uq * 4 + j;
          float gi = sG[(0 * 64 + pb) * 17 + u] + (float)gI.h[j];
          float gf = sG[(1 * 64 + pb) * 17 + u] + (float)gF.h[j];
          float gg = sG[(2 * 64 + pb) * 17 + u] + (float)gG.h[j];
          float go = sG[(3 * 64 + pb) * 17 + u] + (float)gO.h[j];
          float cn = sigf(gf) * cst[j] + sigf(gi) * tanh_(gg);
          float hn = sigf(go) * tanh_(cn);
          cst[j] = cn;
          outp.h[j] = (f16)hn;
        }
        stU64((ull*)h0seq + (size_t)(t + 1) * 8192 + pb * 128 + utile * 4 + uq, outp.u);
      }
      signalDone(cnt + (size_t)t * 128, bid & 7);
    }
  } else if (bid < 96) {  // ---------- layer 1 (split-phase) ----------
    f16 (*sW2)[8][32][72] = (f16(*)[8][32][72])smem;
    f16 (*sA)[64][72] = (f16(*)[64][72])(smem + 73728);
    float* sG = (float*)(smem + 73728);   // [4][64][9]
    const int utile = bid - 32;
    const int mh = w >> 1, ns = w & 1;
    { int mat = tid >> 7;
      int r = (tid >> 2) & 31, ch = tid & 3;
      int grow = (r >> 3) * 512 + utile * 8 + (r & 7);
      const f16* Wsrc = (mat == 0) ? wih1 : whh1;
      for (int c = 0; c < 8; ++c)
        stageRow(Wsrc + (size_t)grow * 512 + c * 64 + ch * 16, &sW2[mat][c][r][0], ch);
    }
    const int pb = tid >> 2, pup = tid & 3;
    float badd[4][2];
#pragma unroll
    for (int g = 0; g < 4; ++g)
#pragma unroll
      for (int j = 0; j < 2; ++j) {
        int rr = g * 512 + utile * 8 + pup * 2 + j;
        badd[g][j] = bih1[rr] + bhh1[rr];
      }
    float cst[2] = {0.f, 0.f};
    unsigned* line1 = cnt + (size_t)T * 128;
    for (int t = 0; t < T; ++t) {
      wait8(cnt + (size_t)t * 128, 4);
      stageAu((const ull*)h0seq + (size_t)(t + 1) * 8192, sA, tid);   // h0(t)
      if (t > 0) wait8(line1 + (size_t)(t - 1) * 128, 8);
      else       __syncthreads();
      ull rg[8][4];                                                    // h1(t-1) prefetch
      { const ull* s1p = (const ull*)h1seq + (size_t)t * 8192 + (tid >> 2) * 128 + (tid & 3) * 4;
#pragma unroll
        for (int c = 0; c < 8; ++c)
#pragma unroll
          for (int q = 0; q < 4; ++q) rg[c][q] = ldU(s1p + c * 16 + q);
      }
      f32x4 acc[2] = {};
      kloop32(sW2[0], sA, mh, ns, m16, g4, acc);
      __syncthreads();
      { int row = tid >> 2, ch = tid & 3;
#pragma unroll
        for (int c = 0; c < 8; ++c) {
          f16* d = &sA[c][row][0];
          *(ull*)(d +  0 + ch * 4) = rg[c][0];
          *(ull*)(d + 16 + ch * 4) = rg[c][1];
          *(ull*)(d + 32 + ch * 4) = rg[c][2];
          *(ull*)(d + 48 + ch * 4) = rg[c][3];
        }
      }
      __syncthreads();
      kloop32(sW2[1], sA, mh, ns, m16, g4, acc);
      __syncthreads();
      { int nl = ns * 16 + m16;
#pragma unroll
        for (int mt = 0; mt < 2; ++mt)
#pragma unroll
          for (int r = 0; r < 4; ++r) {
            int b = mh * 32 + mt * 16 + g4 * 4 + r;
            sG[((nl >> 3) * 64 + b) * 9 + (nl & 7)] = acc[mt][r];
          }
      }
      __syncthreads();
      {
        H2 outp;
#pragma unroll
        for (int j = 0; j < 2; ++j) {
          int u = pup * 2 + j;
          float gi = sG[(0 * 64 + pb) * 9 + u] + badd[0][j];
          float gf = sG[(1 * 64 + pb) * 9 + u] + badd[1][j];
          float gg = sG[(2 * 64 + pb) * 9 + u] + badd[2][j];
          float go = sG[(3 * 64 + pb) * 9 + u] + badd[3][j];
          float cn = sigf(gf) * cst[j] + sigf(gi) * tanh_(gg);
          float hn = sigf(go) * tanh_(cn);
          cst[j] = cn;
          outp.h[j] = (f16)hn;
        }
        stU32((unsigned*)h1seq + (size_t)(t + 1) * 16384 + pb * 256 + utile * 4 + pup, outp.u);
      }
      signalDone(line1 + (size_t)t * 128, bid & 7);
    }
  } else if (bid < 224) {  // ---------- conv role ----------
    convTile(smem, convBase + bid - 96, cfT, wc9, cb, xemH);
  } else if (mode == 0) {  // ---------- enc: X0de producer (tt>=1), free-running ----------
    const int rid = bid - 224;
    f16 (*sW)[64][72] = (f16(*)[64][72])smem;
    f16 (*sA)[64][72] = (f16(*)[64][72])(smem + 73728);
    { int r = tid >> 2, ch = tid & 3;
      for (int c = 0; c < 8; ++c)
        stageRow(wihD0 + (size_t)(rid * 64 + r) * 512 + c * 64 + ch * 16, &sW[c][r][0], ch);
    }
    const int e = rid * 64 + w * 16 + m16;
    const float bias_e = bihD0[e] + bhhD0[e];
    const int arow = tid >> 2;
    __syncthreads();
    for (int tt = 1; tt < 32; ++tt) {
      const f16* rowSrc = (tt == 1) ? emb + (size_t)95 * 512
                                    : emb + (size_t)tgt[arow * 30 + tt - 2] * 512;
      stageAp(rowSrc, sA, tid);
      __syncthreads();
      f32x4 acc[4] = {};
      kloop64((const f16*)sW, sA, w, m16, g4, acc);
      __syncthreads();
#pragma unroll
      for (int mt = 0; mt < 4; ++mt)
#pragma unroll
        for (int r = 0; r < 4; ++r)
          X0de[((size_t)tt * 64 + mt * 16 + g4 * 4 + r) * 2048 + e] = (f16)(acc[mt][r] + bias_e);
      __syncthreads();
    }
  } else {  // ---------- dec: X0de t=0 (4 n-tiles) then gemmG chase (8 blocks) ----------
    const int g = bid - 224;
    f16* sWg = (f16*)smem;                               // [8][64][72]
    f16 (*sA)[64][72] = (f16(*)[64][72])(smem + 73728);
    // phase 1: X0de t=0 — A (holistic) staged once, 4 n-tiles sequentially
    stageAp(x_t0 + (size_t)(tid >> 2) * 512, sA, tid);
    __syncthreads();
    for (int q = 0; q < 4; ++q) {
      const int rid = g * 4 + q;
      { int r = tid >> 2, ch = tid & 3;
        for (int c = 0; c < 8; ++c)
          stageRow(wihD0 + (size_t)(rid * 64 + r) * 512 + c * 64 + ch * 16,
                   sWg + ((size_t)(c * 64 + r)) * 72, ch);
      }
      __syncthreads();
      f32x4 acc[4] = {};
      kloop64(sWg, sA, w, m16, g4, acc);
      const int e = rid * 64 + w * 16 + m16;
      const float bias_e = bihD0[e] + bhhD0[e];
#pragma unroll
      for (int mt = 0; mt < 4; ++mt)
#pragma unroll
        for (int r = 0; r < 4; ++r)
          X0de[((size_t)(mt * 16 + g4 * 4 + r)) * 2048 + e] = (f16)(acc[mt][r] + bias_e);
      __syncthreads();
    }
    signalDone(cnt + (size_t)(2 * T) * 128, g);
    // phase 2: gemmG chase
    { int r = tid >> 2, ch = tid & 3;
      for (int c = 0; c < 8; ++c)
        stageRow(awh + (size_t)(g * 64 + r) * 512 + c * 64 + ch * 16,
                 sWg + ((size_t)(c * 64 + r)) * 72, ch);
    }
    const int e = g * 64 + w * 16 + m16;
    const float gb = gbias[e];
    __syncthreads();
    unsigned* line1 = cnt + (size_t)T * 128;
    for (int t = 0; t < T; ++t) {
      wait8(line1 + (size_t)t * 128, 8);
      stageAu((const ull*)h1seq + (size_t)(t + 1) * 8192, sA, tid);
      __syncthreads();
      f32x4 acc[4] = {};
      kloop64(sWg, sA, w, m16, g4, acc);
      __syncthreads();
#pragma unroll
      for (int mt = 0; mt < 4; ++mt)
#pragma unroll
        for (int r = 0; r < 4; ++r)
          gAll[(size_t)(t * 64 + mt * 16 + g4 * 4 + r) * 512 + e] = (f16)(acc[mt][r] + gb);
    }
  }
}

// ---------------- batched attention post-pass ----------------

__global__ __launch_bounds__(256) void k_scoreAll(
    const f16* __restrict__ xemH, const f16* __restrict__ gAll,
    const float* __restrict__ wv, float* __restrict__ esc)
{
  __shared__ f16 sX[20][512];
  const int tid = threadIdx.x, lane = tid & 63, w = tid >> 6;
  const int tile = blockIdx.x, b = blockIdx.y;
  for (int i = tid; i < 20 * 64; i += 256) {
    int row = i >> 6, seg = i & 63;
    *(f16x8*)&sX[row][seg * 8] =
        *(const f16x8*)(xemH + ((size_t)(b * 240 + tile * 20 + row)) * 512 + seg * 8);
  }
  float w8[8];
  { const float4* wp = (const float4*)(wv + lane * 8);
    float4 wa = wp[0], wb = wp[1];
    w8[0] = wa.x; w8[1] = wa.y; w8[2] = wa.z; w8[3] = wa.w;
    w8[4] = wb.x; w8[5] = wb.y; w8[6] = wb.z; w8[7] = wb.w; }
  __syncthreads();
  for (int t = 0; t < 32; ++t) {
    f16x8 gv = *(const f16x8*)(gAll + ((size_t)(t * 64 + b)) * 512 + lane * 8);
    float g8[8];
#pragma unroll
    for (int j = 0; j < 8; ++j) g8[j] = (float)gv[j];
#pragma unroll
    for (int i = 0; i < 5; ++i) {
      int rr = i * 4 + w;
      f16x8 xv = *(const f16x8*)&sX[rr][lane * 8];
      float s = 0.f;
#pragma unroll
      for (int j = 0; j < 8; ++j) s += tanh_((float)xv[j] + g8[j]) * w8[j];
#pragma unroll
      for (int m = 32; m; m >>= 1) s += __shfl_xor(s, m);
      if (lane == 0) esc[((size_t)(t * 64 + b)) * 240 + tile * 20 + rr] = s;
    }
  }
}

__global__ __launch_bounds__(256) void k_smctx(
    const float* __restrict__ esc, const f16* __restrict__ cfT,
    const f16* __restrict__ h1seq, f16* __restrict__ ctx)
{
  __shared__ float aAl[8][240];
  const int tid = threadIdx.x, lane = tid & 63, w = tid >> 6;
  const int tq = blockIdx.x, b = blockIdx.y;
  for (int half = 0; half < 2; ++half) {
    int tt = w + half * 4;
    int t = tq * 8 + tt;
    const float* er = esc + ((size_t)(t * 64 + b)) * 240;
    float v[4];
    float mx = -1e30f;
#pragma unroll
    for (int q = 0; q < 4; ++q) {
      int p = lane + q * 64;
      v[q] = (p < 240) ? er[p] : -1e30f;
      mx = fmaxf(mx, v[q]);
    }
#pragma unroll
    for (int m = 32; m; m >>= 1) mx = fmaxf(mx, __shfl_xor(mx, m));
    float sum = 0.f;
#pragma unroll
    for (int q = 0; q < 4; ++q) { v[q] = __expf(v[q] - mx); sum += v[q]; }
#pragma unroll
    for (int m = 32; m; m >>= 1) sum += __shfl_xor(sum, m);
    float inv = 1.f / sum;
#pragma unroll
    for (int q = 0; q < 4; ++q) {
      int p = lane + q * 64;
      if (p < 240) aAl[tt][p] = v[q] * inv;
    }
  }
  __syncthreads();
  float acc[8][2] = {};
  const f16* cb = cfT + (size_t)b * 240 * 512;
  for (int p = 0; p < 240; ++p) {
    H2 cw; cw.u = *(const unsigned*)(cb + (size_t)p * 512 + tid * 2);
    float c0 = (float)cw.h[0], c1 = (float)cw.h[1];
#pragma unroll
    for (int tt = 0; tt < 8; ++tt) {
      float a = aAl[tt][p];
      acc[tt][0] += a * c0;
      acc[tt][1] += a * c1;
    }
  }
#pragma unroll
  for (int tt = 0; tt < 8; ++tt) {
    int t = tq * 8 + tt;
    size_t r = (size_t)(t * 64 + b);
    H2 o; o.h[0] = (f16)acc[tt][0]; o.h[1] = (f16)acc[tt][1];
    *(unsigned*)(ctx + r * 1024 + 512 + tid * 2) = o.u;
    *(unsigned*)(ctx + r * 1024 + tid * 2) =
        *(const unsigned*)(h1seq + (size_t)(t + 1) * HB + b * 512 + tid * 2);
  }
}

// fused logits GEMM + log-softmax + NLL; grid 32 (one block per t)
__global__ __launch_bounds__(256) void k_logit(
    const f16* __restrict__ A,      // ctxAll [2048][1024]
    const f16* __restrict__ W,      // outwH [128][1024] (rows >=96 garbage)
    const float* __restrict__ bias, const int* __restrict__ tgt,
    float* __restrict__ nllb)
{
  __shared__ f16 At[64][72];
  __shared__ f16 Bt[2][64][72];
  __shared__ float sL[64][100];
  const int tid = threadIdx.x, lane = tid & 63, g = tid >> 6;
  const int m16 = lane & 15, g4 = lane >> 4;
  const int t = blockIdx.x;
  const size_t arow0 = (size_t)t * 64;
  f32x4 acc[2][4] = {};

  for (int k0 = 0; k0 < 1024; k0 += 64) {
    __syncthreads();
    { int row = tid >> 2, ch = tid & 3;
      stageRow(A + (arow0 + row) * 1024 + k0 + ch * 16, &At[row][0], ch);
      stageRow(W + (size_t)row * 1024 + k0 + ch * 16, &Bt[0][row][0], ch);
      stageRow(W + (size_t)(64 + row) * 1024 + k0 + ch * 16, &Bt[1][row][0], ch); }
    __syncthreads();
#pragma unroll
    for (int n2 = 0; n2 < 2; ++n2)
#pragma unroll
      for (int half = 0; half < 2; ++half) {
        f16x8 bf = *(const f16x8*)&Bt[n2][g * 16 + m16][g4 * 16 + half * 8];
        f16x4 bl = lo4(bf), bh = hi4(bf);
#pragma unroll
        for (int mt = 0; mt < 4; ++mt) {
          f16x8 af = *(const f16x8*)&At[mt * 16 + m16][g4 * 16 + half * 8];
          acc[n2][mt] = mfma16(lo4(af), bl, acc[n2][mt]);
          acc[n2][mt] = mfma16(hi4(af), bh, acc[n2][mt]);
        }
      }
  }
  __syncthreads();
#pragma unroll
  for (int n2 = 0; n2 < 2; ++n2) {
    int e = n2 * 64 + g * 16 + m16;
    if (e < 96) {
      float be = bias[e];
#pragma unroll
      for (int mt = 0; mt < 4; ++mt)
#pragma unroll
        for (int r = 0; r < 4; ++r)
          sL[mt * 16 + g4 * 4 + r][e] = acc[n2][mt][r] + be;
    }
  }
  __syncthreads();
  if (tid < 64) {
    int b = tid;
    int jj = 31;
    for (int q = 1; q <= 30; ++q)
      if (tgt[b * 30 + q - 1] == 0) { jj = q; break; }
    int tok = (t == 0 || t == 31) ? 0 : tgt[b * 30 + t - 1];
    if (t == jj) tok = 95;
    float val = 0.f;
    if (tok != 0) {
      float mx = -1e30f;
      for (int j = 0; j < 96; ++j) mx = fmaxf(mx, sL[b][j]);
      float s = 0.f;
      for (int j = 0; j < 96; ++j) s += __expf(sL[b][j] - mx);
      val = mx + __logf(s) - sL[b][tok];
    }
    nllb[t * 64 + b] = val;
  }
}

// final masked-mean loss
__global__ void k_loss(const float* __restrict__ nllb, const int* __restrict__ tgt,
                       float* __restrict__ out) {
  __shared__ float sa[256], sb[256];
  int tid = threadIdx.x;
  float a = 0.f, m = 0.f;
  for (int i = tid; i < 2048; i += 256) a += nllb[i];
  if (tid < 64) {
    int b = tid;
    int jj = 31;
    for (int q = 1; q <= 30; ++q)
      if (tgt[b * 30 + q - 1] == 0) { jj = q; break; }
    int cnt = 0;
    for (int t = 1; t <= 30; ++t) {
      int v = tgt[b * 30 + t - 1];
      if (t == jj) v = 95;
      if (v != 0) ++cnt;
    }
    if (jj == 31) ++cnt;
    m = (float)cnt;
  }
  sa[tid] = a; sb[tid] = m; __syncthreads();
  for (int s = 128; s; s >>= 1) { if (tid < s) { sa[tid] += sa[tid + s]; sb[tid] += sb[tid + s]; } __syncthreads(); }
  if (tid == 0) out[0] = sa[0] / sb[0];
}

// ---------------- host ----------------

extern "C" void kernel_launch(void* const* d_in, const int* in_sizes, int n_in,
                              void* d_out, int out_size, void* d_ws, size_t ws_size,
                              hipStream_t stream) {
  (void)in_sizes; (void)n_in; (void)out_size; (void)ws_size;
  const float* conv_f = (const float*)d_in[0];
  const int*   target = (const int*)d_in[1];
  const float* wih_en = (const float*)d_in[2];
  const float* whh_en = (const float*)d_in[3];
  const float* bih_en = (const float*)d_in[4];
  const float* bhh_en = (const float*)d_in[5];
  const float* embed  = (const float*)d_in[6];
  const float* wih_de = (const float*)d_in[7];
  const float* whh_de = (const float*)d_in[8];
  const float* bih_de = (const float*)d_in[9];
  const float* bhh_de = (const float*)d_in[10];
  const float* att_wh = (const float*)d_in[11];
  const float* att_bh = (const float*)d_in[12];
  const float* att_cw = (const float*)d_in[13];
  const float* att_cb = (const float*)d_in[14];
  const float* att_wv = (const float*)d_in[15];
  const float* out_w  = (const float*)d_in[17];
  const float* out_b  = (const float*)d_in[18];
  float* out = (float*)d_out;

  size_t o = 0;
  char* base = (char*)d_ws;
  auto take = [&](size_t bytes) -> void* {
    void* p = base + o;
    o += (bytes + 255) & ~(size_t)255;
    return p;
  };
  const size_t WSZ = (size_t)2048 * 512;
  f16* wihEn = (f16*)take(2 * WSZ * 2);
  f16* whhEn = (f16*)take(2 * WSZ * 2);
  f16* wihDe = (f16*)take(2 * WSZ * 2);
  f16* whhDe = (f16*)take(2 * WSZ * 2);
  f16* awh   = (f16*)take((size_t)512 * 512 * 2);
  f16* emb   = (f16*)take((size_t)96 * 512 * 2);
  f16* wc9   = (f16*)take((size_t)512 * 4608 * 2);
  f16* cfT   = (f16*)take((size_t)64 * 240 * 512 * 2);
  f16* xseq  = (f16*)take((size_t)40 * 64 * 512 * 2);
  f16* xemH  = (f16*)take((size_t)64 * 240 * 512 * 2);
  f16* outwH = (f16*)take((size_t)128 * 1024 * 2);
  f16* X0en  = (f16*)take((size_t)2560 * 2048 * 2);
  f16* X0de  = (f16*)take((size_t)2048 * 2048 * 2);
  f16* h0seqE = (f16*)take((size_t)41 * HB * 2);
  f16* h1seqE = (f16*)take((size_t)41 * HB * 2);
  f16* h0seqD = (f16*)take((size_t)33 * HB * 2);
  f16* h1seqD = (f16*)take((size_t)33 * HB * 2);
  f16* gAll   = (f16*)take((size_t)2048 * 512 * 2);
  float* nllb = (float*)take((size_t)2048 * 4);
  unsigned* cntE = (unsigned*)take(65536);
  unsigned* cntD = (unsigned*)take(65536);
  // aliases onto dead precompute buffers (post-pass runs after their last read)
  float* escAll = (float*)X0en;                          // 2048*240*4
  f16*   ctxAll = X0de;                                  // 2048*1024*2

  // prologue: cfmx + merged prep (wc9/convW/convS/zero)
  k_cfmx<<<dim3(8, 64), 256, 0, stream>>>(conv_f, cfT, xseq);
  k_prep<<<9488, 256, 0, stream>>>(att_cw, wc9,
                                   wih_en, whh_en, wih_de, whh_de,
                                   wihEn, whhEn, wihDe, whhDe,
                                   att_wh, embed, out_w, awh, emb, outwH,
                                   (unsigned*)h0seqE, (unsigned*)h1seqE,
                                   (unsigned*)h0seqD, (unsigned*)h1seqD, cntE, cntD);

  // encoder X0 then persistent encoder (+ conv 0..127 + X0de tt>=1 producers)
  k_gemmX<<<dim3(40, 32), 256, 0, stream>>>(xseq, wihEn, bih_en, bhh_en, X0en);
  k_lstm<<<256, 256, 0, stream>>>(40, 0, X0en, whhEn, wihEn + WSZ, whhEn + WSZ,
                                  bih_en + 2048, bhh_en + 2048, h0seqE, h1seqE, cntE,
                                  cfT, wc9, att_cb, xemH, 0,
                                  X0de, wihDe, bih_de, bhh_de, emb, target,
                                  nullptr, nullptr, nullptr, nullptr);

  // persistent decoder (+ conv 128..255 + X0de t=0 + gemmG chase)
  k_lstm<<<232, 256, 0, stream>>>(32, 1, X0de, whhDe, wihDe + WSZ, whhDe + WSZ,
                                  bih_de + 2048, bhh_de + 2048, h0seqD, h1seqD, cntD,
                                  cfT, wc9, att_cb, xemH, 128,
                                  X0de, wihDe, bih_de, bhh_de, emb, target,
                                  h1seqE + (size_t)40 * HB,
                                  awh, att_bh, gAll);

  // batched attention + fused logits/NLL post-pass
  k_scoreAll<<<dim3(12, 64), 256, 0, stream>>>(xemH, gAll, att_wv, escAll);
  k_smctx<<<dim3(4, 64), 256, 0, stream>>>(escAll, cfT, h1seqD, ctxAll);
  k_logit<<<32, 256, 0, stream>>>(ctxAll, outwH, out_b, target, nllb);
  k_loss<<<1, 256, 0, stream>>>(nllb, target, out);
}